// Round 8
// baseline (21.274 us; speedup 1.0000x reference)
//
#include <hip/hip_runtime.h>
#include <math.h>

#define NGRID 1000
#define HPAD 68        // sH row stride (floats): 272B, 16B-aligned

__device__ __forceinline__ float rdl(float v, int i) {
    return __uint_as_float(__builtin_amdgcn_readlane(__float_as_uint(v), i));
}
__device__ __forceinline__ float frcp(float x) { return __builtin_amdgcn_rcpf(x); }
__device__ __forceinline__ float fsqrt(float x) { return __builtin_amdgcn_sqrtf(x); }

// ================= Kernel A: MLP -> latents (B x 6) =================
#define ABLOCK 256
#define AWPB 4         // waves per block, 4 rows per wave -> 16 rows/block

__global__ __launch_bounds__(ABLOCK) void mlp_kernel(
    const float* __restrict__ x,
    const float* __restrict__ W1, const float* __restrict__ b1,
    const float* __restrict__ W2, const float* __restrict__ b2,
    const float* __restrict__ W3, const float* __restrict__ b3,
    const float* __restrict__ W4, const float* __restrict__ b4,
    float* __restrict__ lat, int B)
{
    // W2/W3 staged LINEAR (row-major, as in global). Column read j + i*64:
    // per instr all lanes share i -> bank = j%32, 2 lanes/bank = free, and
    // the address is base+imm (i unrolled) -> zero address VALU.
    __shared__ __attribute__((aligned(16))) float sW2[64*64];
    __shared__ __attribute__((aligned(16))) float sW3[64*64];
    __shared__ __attribute__((aligned(16))) float sW4[6*64 + 8];
    __shared__ __attribute__((aligned(16))) float sH[AWPB][4][HPAD];

    const int tid = threadIdx.x;
    {
        const float4* s2 = (const float4*)W2;
        const float4* s3 = (const float4*)W3;
        float4* d2 = (float4*)sW2;
        float4* d3 = (float4*)sW3;
        #pragma unroll
        for (int c = 0; c < 4; ++c) {
            d2[c*256 + tid] = s2[c*256 + tid];
            d3[c*256 + tid] = s3[c*256 + tid];
        }
        if (tid < 96) ((float4*)sW4)[tid] = ((const float4*)W4)[tid];
    }
    __syncthreads();   // the only barrier

    const int lane = tid & 63;
    const int widx = tid >> 6;
    const int j    = lane;
    const int row0 = (blockIdx.x * AWPB + widx) * 4;

    const float b1j = b1[j], b2j = b2[j], b3j = b3[j];

    // x for 4 rows via lanes 0..19 (clamped), distributed by readlane
    int xidx = row0*5 + lane;
    const int xmax = B*5 - 1;
    if (xidx > xmax) xidx = xmax;
    const float xv = x[xidx];

    // ---- layer 1: 5 -> 64, exact fma chain (bias first, i ascending) ----
    float h0 = b1j, h1 = b1j, h2 = b1j, h3 = b1j;
    #pragma unroll
    for (int i = 0; i < 5; ++i) {
        const float w1i = W1[(i << 6) + j];
        h0 = fmaf(rdl(xv, i     ), w1i, h0);
        h1 = fmaf(rdl(xv, 5 + i ), w1i, h1);
        h2 = fmaf(rdl(xv, 10 + i), w1i, h2);
        h3 = fmaf(rdl(xv, 15 + i), w1i, h3);
    }
    h0 = fmaxf(h0, 0.0f); h1 = fmaxf(h1, 0.0f);
    h2 = fmaxf(h2, 0.0f); h3 = fmaxf(h3, 0.0f);

    // ---- layer 2: 64 -> 64 (weights b32 w/ imm offset, h via readlane) ----
    {
        const float* wcol = sW2 + j;
        float a0 = b2j, a1 = b2j, a2 = b2j, a3 = b2j;
        #pragma unroll
        for (int i = 0; i < 64; ++i) {
            const float wv = wcol[i << 6];
            a0 = fmaf(rdl(h0, i), wv, a0);
            a1 = fmaf(rdl(h1, i), wv, a1);
            a2 = fmaf(rdl(h2, i), wv, a2);
            a3 = fmaf(rdl(h3, i), wv, a3);
        }
        h0 = fmaxf(a0, 0.0f); h1 = fmaxf(a1, 0.0f);
        h2 = fmaxf(a2, 0.0f); h3 = fmaxf(a3, 0.0f);
    }
    // ---- layer 3 ----
    {
        const float* wcol = sW3 + j;
        float a0 = b3j, a1 = b3j, a2 = b3j, a3 = b3j;
        #pragma unroll
        for (int i = 0; i < 64; ++i) {
            const float wv = wcol[i << 6];
            a0 = fmaf(rdl(h0, i), wv, a0);
            a1 = fmaf(rdl(h1, i), wv, a1);
            a2 = fmaf(rdl(h2, i), wv, a2);
            a3 = fmaf(rdl(h3, i), wv, a3);
        }
        h0 = fmaxf(a0, 0.0f); h1 = fmaxf(a1, 0.0f);
        h2 = fmaxf(a2, 0.0f); h3 = fmaxf(a3, 0.0f);
    }

    // ---- park h; layer 4: 64 -> 6 by lanes 0..23 (r=lane&3, u=lane>>2) ----
    sH[widx][0][j] = h0; sH[widx][1][j] = h1;
    sH[widx][2][j] = h2; sH[widx][3][j] = h3;

    if (lane < 24) {
        const int r = lane & 3, u = lane >> 2;
        const float* hrow = sH[widx][r];
        float acc = b4[u];
        #pragma unroll
        for (int i = 0; i < 64; ++i)
            acc = fmaf(hrow[i], sW4[i*6 + u], acc);
        const int row = row0 + r;
        if (row < B) lat[row*6 + u] = acc;
    }
}

// ============ Kernel B: physics + scan (reads latents) ============
#define BBLOCK 512
#define BWPB 8         // 2 rows per wave -> 16 rows/block, zero LDS

__global__ __launch_bounds__(BBLOCK) void scan_kernel(
    const float* __restrict__ x,
    const float* __restrict__ kin,
    const float* __restrict__ lat,
    float* __restrict__ out, int B)
{
    const int tid  = threadIdx.x;
    const int lane = tid & 63;
    const int widx = tid >> 6;
    const int half = lane >> 5;
    const int la   = lane & 31;
    const int row0 = (blockIdx.x * BWPB + widx) * 2;
    const int row  = row0 + half;
    const bool act = (row < B);
    const int rowc = act ? row : (B - 1);

    const float i00 = kin[0], i01 = kin[1], i02 = kin[2];
    const float invRT = 1.0f / 2478.8191f;
    const float ksr0 = ((-kin[3]) * 96485.33f) * invRT;
    const float ksr1 = ((-kin[4]) * 96485.33f) * invRT;
    const float ksr2 = ((-kin[5]) * 96485.33f) * invRT;
    const float stepV = 1.25f / 999.0f;

    // ---- physics, redundantly in all 32 lanes of the half (no shuffles;
    //      all lanes compute bitwise-identical values) ----
    const float lat0 = lat[rowc*6 + 0];
    const float lat1 = lat[rowc*6 + 1];
    const float lat2 = lat[rowc*6 + 2];
    const float lat3 = lat[rowc*6 + 3];
    const float lat4 = lat[rowc*6 + 4];
    const float lat5 = lat[rowc*6 + 5];

    const float rr   = 4e-8f * __expf(lat0);
    const float epsv = frcp(1.0f + __expf(-lat1));
    const float zlt  = x[rowc*5 + 3];
    const float Lf   = zlt * frcp(1.0f - epsv);
    const float Kdl  = __expf(lat2);
    const float z0 = 2.0f*lat3, z1 = 2.0f*lat4, z2 = 2.0f*lat5;
    const float mz = fmaxf(z0, fmaxf(z1, z2));
    const float p0 = __expf(z0 - mz), p1 = __expf(z1 - mz), p2 = __expf(z2 - mz);
    const float ips = frcp(p0 + p1 + p2);
    const float th0 = p0*ips, th1 = p1*ips, th2 = p2*ips;
    const float irr = frcp(rr);
    const float gdl   = (Kdl * 1.91e-9f) * (epsv * fsqrt(epsv)) * irr;
    const float asurf = (3.0f * (1.0f - epsv)) * Lf * irr;
    const float c0 = (i00*th0)*asurf, c1 = (i01*th1)*asurf, c2 = (i02*th2)*asurf;
    const float il0 = (((2.0f*96485.33f)*34.0f)*gdl)*0.1f;
    const float il1 = (((12.0f*96485.33f)*34.0f)*gdl)*0.1f;
    const float invl0 = frcp(il0), invl1 = frcp(il1);

    auto evaltot = [&](int v) -> float {
        const float V = -1.25f + stepV * (float)v;
        const float t0 = __expf(ksr0 * (V + 0.11f));
        const float t1 = __expf(ksr1 * (V - 0.08f));
        const float t2 = __expf(ksr2 * V);
        const float ie0 = frcp(frcp(c0*t0) + invl0);
        const float ie1 = frcp(frcp(c1*t1) + invl1);
        const float ie2 = c2*t2;       // i_lim[2] = inf
        return ie0 + ie1 + ie2;
    };

    // coarse: 32 points stride 32; i_tot weakly decreasing in v
    const int vc = la << 5;            // 0..992
    const float totc = evaltot(vc);
    float bd = fabsf(totc - 200.0f);
    int bidx = vc;

    const unsigned long long mall = __ballot(totc >= 200.0f);
    const unsigned int m32 = (unsigned int)(mall >> (half << 5));
    const int kstar = m32 ? (31 - __builtin_clz(m32)) : 0;
    const int base = kstar << 5;

    // fine: 32 points (base, base+32]; coarse candidates cover the rest
    {
        int vf = base + 1 + la;
        if (vf > NGRID-1) vf = NGRID-1;
        const float totf = evaltot(vf);
        const float df = fabsf(totf - 200.0f);
        if (df < bd || (df == bd && vf < bidx)) { bd = df; bidx = vf; }
    }

    // lexicographic (d, idx) butterfly within each 32-lane half
    #pragma unroll
    for (int off = 16; off; off >>= 1) {
        const float od = __shfl_xor(bd, off, 64);
        const int   oi = __shfl_xor(bidx, off, 64);
        if (od < bd || (od == bd && oi < bidx)) { bd = od; bidx = oi; }
    }

    // ---- select + FE ----
    const float V = -1.25f + stepV * (float)bidx;
    const float t0 = __expf(ksr0 * (V + 0.11f));
    const float t1 = __expf(ksr1 * (V - 0.08f));
    const float t2 = __expf(ksr2 * V);
    const float ie0 = frcp(frcp(c0*t0) + invl0);
    const float ie1 = frcp(frcp(c1*t1) + invl1);
    const float ie2 = c2*t2;
    const float itr = frcp(ie0 + ie1 + ie2);
    if (act && la < 2) {
        out[row*2 + la] = (la == 0) ? (ie1*itr) : (ie0*itr);
    }
}

extern "C" void kernel_launch(void* const* d_in, const int* in_sizes, int n_in,
                              void* d_out, int out_size, void* d_ws, size_t ws_size,
                              hipStream_t stream) {
    const float* x   = (const float*)d_in[0];
    const float* W1  = (const float*)d_in[1];
    const float* b1  = (const float*)d_in[2];
    const float* W2  = (const float*)d_in[3];
    const float* b2  = (const float*)d_in[4];
    const float* W3  = (const float*)d_in[5];
    const float* b3  = (const float*)d_in[6];
    const float* W4  = (const float*)d_in[7];
    const float* b4  = (const float*)d_in[8];
    const float* kin = (const float*)d_in[9];
    float* out = (float*)d_out;
    float* lat = (float*)d_ws;           // B x 6 fp32 = 384 KB
    const int B = in_sizes[0] / 5;

    const int gridA = (B + AWPB*4 - 1) / (AWPB*4);   // 1024
    mlp_kernel<<<gridA, ABLOCK, 0, stream>>>(x, W1, b1, W2, b2, W3, b3, W4, b4, lat, B);

    const int gridB = (B + BWPB*2 - 1) / (BWPB*2);   // 1024
    scan_kernel<<<gridB, BBLOCK, 0, stream>>>(x, kin, lat, out, B);
}